// Round 2
// baseline (415.122 us; speedup 1.0000x reference)
//
#include <hip/hip_runtime.h>

// LSTMPricePredictor: B=4096, T=512, IN=1, H=50, 2 layers + FC(50->1)
// R18 = R17 restructured from 13 waves x 1 M-tile to 7 waves x 2 M-tiles.
//   Theory: step time ~1695 cyc is phase-SUM (lockstep barrier): post-barrier
//   LDS read burst (52 ds_read_b128, ~620 cyc) serializes before MFMA/EW.
//   2-tile waves amortize the identical B-fragments over 12 MFMAs: reads
//   drop to 28/step, barrier width 13->7, per-wave ILP doubles. Per-SIMD
//   trans straggler (56 instr ~ 520 cyc) is invariant -- that's the floor.
// Carried from R17: x rank-1 via LDS stage, branch-peeled loop, bias as
//   MFMA C-operand, unconditional h stores into dead k>=50 slots, 2-rcp
//   cell_update with c pre-scaled by 2*log2e, raw v_exp_f32.

typedef _Float16 half8 __attribute__((ext_vector_type(8)));
typedef float    f32x4 __attribute__((ext_vector_type(4)));

#define TT    512
#define HID   50
#define NB    16         // batch rows per block
#define XST   17         // xs row stride in floats (bank-conflict-free)
#define NW    7          // waves
#define NT    2          // M-tiles per wave (7*2=14 tiles >= 13 needed)
#define NTHR  (NW * 64)  // 448 threads
#define LOG2E 1.44269504f

// Weight A-fragment: lane's 8 fp16 for K-chunk `chunk`, pre-scaled by the
// gate's exp2 factor. Tile g covers rows 16g..16g+15; row m -> gate = m&3,
// cell = 4g + (m>>2). W is (200 x 50): element [gate*50+cell][k]. Rows with
// cell >= 50 and k-slots >= 50 are zero (dead lanes multiply by zero).
__device__ __forceinline__ float4 make_wfrag(const float* W, int gate, int cell,
                                             int chunk, int quad, float scale) {
    half8 hv = {};
    #pragma unroll
    for (int j = 0; j < 8; ++j) {
        const int k = 32 * chunk + 8 * quad + j;
        float v = 0.0f;
        if (cell < HID && k < HID) v = W[(gate * HID + cell) * HID + k] * scale;
        hv[j] = (_Float16)v;
    }
    return __builtin_bit_cast(float4, hv);
}

// Shared-rcp LSTM cell update on pre-scaled gates, RAW hardware exp2.
//   a0 = -i*log2e, a1 = -f*log2e, a2 = 2g*log2e, a3 = -o*log2e.
// ct = c * 2*log2e carried across steps. Common denominator:
//   ct' = [ct*p + K(eg-1)*q] / (p*q),  p=(1+ei)(1+eg), q=(1+ef), K=2log2e.
// Worst-case p*q <= 2^82 -- no overflow. Dead lanes: all-zero gates give
// ei=ef=eg=eo=1 -> ct stays 0, h = 0 exactly.
__device__ __forceinline__ float cell_update(const f32x4 a, float& ct) {
    const float K  = 2.0f * LOG2E;
    const float ei = __builtin_amdgcn_exp2f(a[0]);   // e^{-i}
    const float ef = __builtin_amdgcn_exp2f(a[1]);   // e^{-f}
    const float eg = __builtin_amdgcn_exp2f(a[2]);   // e^{2g}
    const float eo = __builtin_amdgcn_exp2f(a[3]);   // e^{-o}
    const float p  = (1.0f + ei) * (1.0f + eg);
    const float q  = 1.0f + ef;
    const float t1 = __builtin_fmaf(eg, K, -K);                  // K*(eg-1)
    const float num = __builtin_fmaf(ct, p, t1 * q);
    ct = num * __builtin_amdgcn_rcpf(p * q);                     // K*c'
    const float ec = __builtin_amdgcn_exp2f(ct);                 // e^{2c'}
    return (ec - 1.0f) *
        __builtin_amdgcn_rcpf((1.0f + eo) * (ec + 1.0f));        // sig(o)*tanh(c')
}

#define PIN(f) asm volatile("" : "+v"(f.x), "+v"(f.y), "+v"(f.z), "+v"(f.w));
#define MFMA(af, b, c) __builtin_amdgcn_mfma_f32_16x16x32_f16(__builtin_bit_cast(half8, (af)), (b), (c), 0, 0, 0)

extern "C" __global__ __launch_bounds__(NTHR, 2)
void lstm2_mfma_kernel(const float* __restrict__ x,
                       const float* __restrict__ W_ih0, const float* __restrict__ W_hh0,
                       const float* __restrict__ b_ih0, const float* __restrict__ b_hh0,
                       const float* __restrict__ W_ih1, const float* __restrict__ W_hh1,
                       const float* __restrict__ b_ih1, const float* __restrict__ b_hh1,
                       const float* __restrict__ fc_w, const float* __restrict__ fc_b,
                       float* __restrict__ out)
{
    // h-state in B-fragment layout: element (k, n) at (k>>5)*512 +
    // (((k&31)>>3)*16 + n)*8 + (k&7). k<50 = h; k=50..55 slots are dead
    // (zero A-weights) and absorb the cellD=50..55 junk stores.
    __shared__ _Float16 H0[2][1024];
    __shared__ _Float16 H1[2][1024];
    __shared__ float    xs[TT * XST];     // x staged fp32, [u*XST + col]
    __shared__ float    hfin[56 * NB];    // fp32 h1^(TT) for the FC epilogue

    const int tid  = threadIdx.x;
    const int lane = tid & 63;
    const int wv   = tid >> 6;            // wave 0..6
    const int b0   = blockIdx.x * NB;

    for (int i = tid; i < 1024; i += NTHR) {
        H0[0][i] = (_Float16)0.f; H0[1][i] = (_Float16)0.f;
        H1[0][i] = (_Float16)0.f; H1[1][i] = (_Float16)0.f;
    }
    // One-shot x stage: coalesced global read, stride-17 LDS write.
    for (int i = tid; i < NB * TT; i += NTHR) {
        const int row = i >> 9;           // batch row 0..15
        const int uu  = i & (TT - 1);     // timestep
        xs[uu * XST + row] = x[(size_t)(b0 + row) * TT + uu];
    }

    const int quad = lane >> 4;
    const int col  = lane & 15;           // batch column
    const int mrow = lane & 15;           // A-row within tile
    const int gateA = mrow & 3;
    const float scA = (gateA == 2) ? 2.0f * LOG2E : -LOG2E;

    // ---- per-tile A-fragments (weights, exp2-prescaled), loaded once ----
    float4 A0c0[NT], A0c1[NT], Aic0[NT], Aic1[NT], Ahc0[NT], Ahc1[NT];
    f32x4  bias0[NT], bias1[NT], wx0[NT];
    int    wiT[NT], cdT[NT];
    #pragma unroll
    for (int t = 0; t < NT; ++t) {
        const int g = NT * wv + t;            // global tile 0..13 (13 dead)
        const int cellA = 4 * g + (mrow >> 2);
        A0c0[t] = make_wfrag(W_hh0, gateA, cellA, 0, quad, scA);
        A0c1[t] = make_wfrag(W_hh0, gateA, cellA, 1, quad, scA);
        Aic0[t] = make_wfrag(W_ih1, gateA, cellA, 0, quad, scA);
        Aic1[t] = make_wfrag(W_ih1, gateA, cellA, 1, quad, scA);
        Ahc0[t] = make_wfrag(W_hh1, gateA, cellA, 0, quad, scA);
        Ahc1[t] = make_wfrag(W_hh1, gateA, cellA, 1, quad, scA);

        const int  cellD = 4 * g + quad;      // D ownership: cell, batch=col
        const bool ewok  = (cellD < HID);
        cdT[t] = cellD;
        #pragma unroll
        for (int gg = 0; gg < 4; ++gg) {
            const float s = (gg == 2) ? 2.0f * LOG2E : -LOG2E;
            bias0[t][gg] = ewok ? (b_ih0[gg * HID + cellD] + b_hh0[gg * HID + cellD]) * s : 0.f;
            bias1[t][gg] = ewok ? (b_ih1[gg * HID + cellD] + b_hh1[gg * HID + cellD]) * s : 0.f;
            wx0[t][gg]   = ewok ? W_ih0[gg * HID + cellD] * s : 0.f;
        }
        // h write-back index in B-layout for (cellD, col); cellD 50..55 land
        // in the dead k=50..55 slots (zero A-weights) -> unconditional store.
        wiT[t] = (cellD >> 5) * 512 + (((cellD & 31) >> 3) * 16 + col) * 8 + (cellD & 7);
    }
    #pragma unroll
    for (int t = 0; t < NT; ++t) {
        PIN(A0c0[t]) PIN(A0c1[t]) PIN(Aic0[t]) PIN(Aic1[t]) PIN(Ahc0[t]) PIN(Ahc1[t])
    }

    float ct0[NT] = {0.f, 0.f}, ct1[NT] = {0.f, 0.f};   // c * 2*log2e
    __syncthreads();

    // ---- prologue u=0: layer-0 only, h0^0 = 0 => gates = wx0*x_0 + bias0
    {
        const float xr = xs[col];
        #pragma unroll
        for (int t = 0; t < NT; ++t) {
            f32x4 acc;
            #pragma unroll
            for (int gg = 0; gg < 4; ++gg)
                acc[gg] = __builtin_fmaf(wx0[t][gg], xr, bias0[t][gg]);
            const float h = cell_update(acc, ct0[t]);
            H0[1][wiT[t]] = (_Float16)h;      // h0^1
        }
        __syncthreads();
    }

    // ---- main loop u=1..TT-1: both layers, branch-free ----
    #pragma unroll 2
    for (int u = 1; u < TT; ++u) {
        const int pu = u & 1, pn = pu ^ 1;

        const half8 b0c0 = *(const half8*)(&H0[pu][lane * 8]);
        const half8 b0c1 = *(const half8*)(&H0[pu][512 + lane * 8]);
        const half8 b1c0 = *(const half8*)(&H1[pn][lane * 8]);
        const half8 b1c1 = *(const half8*)(&H1[pn][512 + lane * 8]);
        const float xr   = xs[u * XST + col];

        f32x4 acc0[NT], acc1[NT];
        #pragma unroll
        for (int t = 0; t < NT; ++t) {
            // layer-0: gates0^u (x enters as rank-1 FMA into the C operand)
            f32x4 tv;
            #pragma unroll
            for (int gg = 0; gg < 4; ++gg)
                tv[gg] = __builtin_fmaf(wx0[t][gg], xr, bias0[t][gg]);
            acc0[t] = MFMA(A0c0[t], b0c0, tv);
            acc0[t] = MFMA(A0c1[t], b0c1, acc0[t]);
            // layer-1: gates1 (bias fed directly as C operand)
            acc1[t] = MFMA(Aic0[t], b0c0, bias1[t]);   // Wi1 . h0^u
            acc1[t] = MFMA(Aic1[t], b0c1, acc1[t]);
            acc1[t] = MFMA(Ahc0[t], b1c0, acc1[t]);    // Wh1 . h1^{u-1}
            acc1[t] = MFMA(Ahc1[t], b1c1, acc1[t]);
        }
        #pragma unroll
        for (int t = 0; t < NT; ++t) {
            const float h0n = cell_update(acc0[t], ct0[t]);
            H0[pn][wiT[t]] = (_Float16)h0n;            // h0^{u+1}
            const float h1n = cell_update(acc1[t], ct1[t]);
            H1[pu][wiT[t]] = (_Float16)h1n;            // h1^u
        }
        __syncthreads();
    }

    // ---- epilogue u=TT: layer-1 only -> h1^TT into hfin ----
    {
        const half8 b0c0 = *(const half8*)(&H0[0][lane * 8]);        // h0^TT
        const half8 b0c1 = *(const half8*)(&H0[0][512 + lane * 8]);
        const half8 b1c0 = *(const half8*)(&H1[1][lane * 8]);        // h1^{TT-1}
        const half8 b1c1 = *(const half8*)(&H1[1][512 + lane * 8]);
        #pragma unroll
        for (int t = 0; t < NT; ++t) {
            f32x4 acc1 = MFMA(Aic0[t], b0c0, bias1[t]);
            acc1 = MFMA(Aic1[t], b0c1, acc1);
            acc1 = MFMA(Ahc0[t], b1c0, acc1);
            acc1 = MFMA(Ahc1[t], b1c1, acc1);
            const float h1n = cell_update(acc1, ct1[t]);
            hfin[cdT[t] * NB + col] = h1n;   // cells 50..55 -> unused slots
        }
        __syncthreads();
    }

    // ---------- FC epilogue: out[b] = fc_b + fc_w . h1^(TT)[b,:] ----------
    if (tid < NB) {
        float s = fc_b[0];
        for (int k = 0; k < HID; ++k)
            s += fc_w[k] * hfin[k * NB + tid];
        out[b0 + tid] = s;
    }
}

extern "C" void kernel_launch(void* const* d_in, const int* in_sizes, int n_in,
                              void* d_out, int out_size, void* d_ws, size_t ws_size,
                              hipStream_t stream) {
    (void)in_sizes; (void)n_in; (void)d_ws; (void)ws_size; (void)out_size;
    const float* x     = (const float*)d_in[0];
    const float* W_ih0 = (const float*)d_in[1];
    const float* W_hh0 = (const float*)d_in[2];
    const float* b_ih0 = (const float*)d_in[3];
    const float* b_hh0 = (const float*)d_in[4];
    const float* W_ih1 = (const float*)d_in[5];
    const float* W_hh1 = (const float*)d_in[6];
    const float* b_ih1 = (const float*)d_in[7];
    const float* b_hh1 = (const float*)d_in[8];
    const float* fc_w  = (const float*)d_in[9];
    const float* fc_b  = (const float*)d_in[10];

    dim3 grid(4096 / NB);   // 256 blocks, 1 per CU
    dim3 block(NTHR);       // 7 waves x 2 M-tiles
    lstm2_mfma_kernel<<<grid, block, 0, stream>>>(
        x, W_ih0, W_hh0, b_ih0, b_hh0,
        W_ih1, W_hh1, b_ih1, b_hh1,
        fc_w, fc_b, (float*)d_out);
}